// Round 17
// baseline (627.176 us; speedup 1.0000x reference)
//
#include <hip/hip_runtime.h>
#include <hip/hip_bf16.h>
#include <cmath>
#include <cstdint>

#define H_    24
#define HD_   128
#define D_    3072
#define SIMG_ 2048
#define LTXT_ 512
#define SALL_ 2560
#define NIP_  1024
#define IPD_  2048

using bf16 = __hip_bfloat16;
typedef __bf16 bf16x8 __attribute__((ext_vector_type(8)));
typedef float  f32x4  __attribute__((ext_vector_type(4)));
typedef short  short8 __attribute__((ext_vector_type(8)));
typedef unsigned int uint4v __attribute__((ext_vector_type(4)));

// 1/sqrt(128) * log2(e)  (exp2-domain softmax)
#define QSCALE_ 0.12751741f

// XCD-aware bijective block swizzle, A-panel-resident variant (requires grid % 8 == 0).
// bx OUTER / by INNER within each XCD: each XCD holds 1-2 A row-panels L2-resident
// while W/B panels stream (short reuse distance -> L3-hot).
#define SWZ_BLOCK(bx, by)                                              \
  {                                                                    \
    int _gy = gridDim.y;                                               \
    int _hw = blockIdx.x + blockIdx.y * gridDim.x;                     \
    int _n  = gridDim.x * _gy;                                         \
    int _lid = (_hw & 7) * (_n >> 3) + (_hw >> 3);                     \
    bx = _lid / _gy;                                                   \
    by = _lid % _gy;                                                   \
  }

__device__ __forceinline__ unsigned short f2bf(float f) {
  unsigned int u = __float_as_uint(f);
  unsigned int r = (u + 0x7fffu + ((u >> 16) & 1u)) >> 16;   // RNE
  return (unsigned short)r;
}
__device__ __forceinline__ float bf2f(unsigned short u) {
  return __uint_as_float(((unsigned int)u) << 16);
}
__device__ __forceinline__ unsigned int cvtpk(float lo, float hi) {
  unsigned int pk;
  asm("v_cvt_pk_bf16_f32 %0, %1, %2" : "=v"(pk) : "v"(lo), "v"(hi));
  return pk;
}

__device__ __forceinline__ void gload16(const void* g, void* l) {
  __builtin_amdgcn_global_load_lds(
      (const __attribute__((address_space(1))) unsigned*)g,
      (__attribute__((address_space(3))) unsigned*)l, 16, 0, 0);
}

// NOTE: q/k/V^T head-dim is stored PERMUTED: stored position s of original col c is
// s = (c&15)*8 + (c>>4).  Dot products over d are permutation-invariant; the
// attention O-write maps back to original order.

// ---------------- elementwise cast fp32 -> bf16 ----------------
__global__ void cast_kernel(const float* __restrict__ x, unsigned short* __restrict__ y, int n4) {
  int i = blockIdx.x * blockDim.x + threadIdx.x;
  if (i >= n4) return;
  float4 v = reinterpret_cast<const float4*>(x)[i];
  ushort4 o = make_ushort4(f2bf(v.x), f2bf(v.y), f2bf(v.z), f2bf(v.w));
  reinterpret_cast<ushort4*>(y)[i] = o;
}

// ---------------- dual cast fp32 -> bf16 (two tensors in one dispatch) ----------------
__global__ void cast2_kernel(const float* __restrict__ x1, unsigned short* __restrict__ y1, int n4_1,
                             const float* __restrict__ x2, unsigned short* __restrict__ y2, int n4_2) {
  int i = blockIdx.x * blockDim.x + threadIdx.x;
  const float* x; unsigned short* y;
  if (i < n4_1) { x = x1; y = y1; }
  else { i -= n4_1; if (i >= n4_2) return; x = x2; y = y2; }
  float4 v = reinterpret_cast<const float4*>(x)[i];
  ushort4 o = make_ushort4(f2bf(v.x), f2bf(v.y), f2bf(v.z), f2bf(v.w));
  reinterpret_cast<ushort4*>(y)[i] = o;
}

// ------- transpose + cast (up to 3 weights): W[R][C] f32 -> Wt slab z: [C][R] bf16 -------
__global__ __launch_bounds__(512)
void transpose_cast3_kernel(const float* __restrict__ W0, const float* __restrict__ W1,
                            const float* __restrict__ W2, unsigned short* __restrict__ Wt,
                            int R, int C) {
  __shared__ float tile[64][69];
  const float* W = blockIdx.z == 0 ? W0 : (blockIdx.z == 1 ? W1 : W2);
  unsigned short* dst = Wt + (size_t)blockIdx.z * R * C;
  int bx = blockIdx.x * 64, by = blockIdx.y * 64;
  int tx = threadIdx.x, ty = threadIdx.y;   // (16, 32)
#pragma unroll
  for (int i = 0; i < 2; i++) {
    int r = ty + 32 * i;
    float4 v = *reinterpret_cast<const float4*>(&W[(size_t)(by + r) * C + bx + tx * 4]);
    tile[r][tx * 4 + 0] = v.x; tile[r][tx * 4 + 1] = v.y;
    tile[r][tx * 4 + 2] = v.z; tile[r][tx * 4 + 3] = v.w;
  }
  __syncthreads();
  int tid = ty * 16 + tx;
  int c = tid >> 3, r0 = (tid & 7) * 8;
  short8 o;
#pragma unroll
  for (int j = 0; j < 8; j++) o[j] = (short)f2bf(tile[r0 + j][c]);
  *reinterpret_cast<short8*>(&dst[(size_t)(bx + c) * R + by + r0]) = o;
}

// ---------------- 2-phase GEMM core: 128x128 tile, BK=64, double-buffered LDS ----------
// LDS content: L[row][seg] = G[row][seg ^ (row&7)] (16B segs); reads XOR the same mask.
// Per iter: issue STAGE(next) first, compute current, single barrier (drains vmcnt).
__device__ __forceinline__ void gemm_core64_db(const bf16* __restrict__ Ab,
                                               const bf16* __restrict__ Bb, int K,
                                               bf16 (*Alds)[128 * 64], bf16 (*Blds)[128 * 64],
                                               int t, int wid, int l16, int lg,
                                               f32x4 (&acc)[2][8]) {
  auto stage = [&](int b, int kt) {
    char* AldsB = (char*)Alds[b] + t * 16;
    char* BldsB = (char*)Blds[b] + t * 16;
#pragma unroll
    for (int p = 0; p < 4; p++) {
      gload16(Ab + (size_t)(32 * p) * K + kt, AldsB + p * 4096);
      gload16(Bb + (size_t)(32 * p) * K + kt, BldsB + p * 4096);
    }
  };
  int nk = K >> 6;
  stage(0, 0);
  __syncthreads();
  for (int i = 0; i < nk; i++) {
    int b = i & 1;
    if (i + 1 < nk) stage(b ^ 1, (i + 1) << 6);
#pragma unroll
    for (int kb = 0; kb < 2; kb++) {
      bf16x8 af[2], bfr[8];
#pragma unroll
      for (int mi = 0; mi < 2; mi++) {
        int r = wid * 32 + mi * 16 + l16;
        af[mi] = *reinterpret_cast<const bf16x8*>(
            (char*)Alds[b] + r * 128 + ((lg * 16 + kb * 64) ^ ((r & 7) << 4)));
      }
#pragma unroll
      for (int ni = 0; ni < 8; ni++) {
        int r = ni * 16 + l16;
        bfr[ni] = *reinterpret_cast<const bf16x8*>(
            (char*)Blds[b] + r * 128 + ((lg * 16 + kb * 64) ^ ((r & 7) << 4)));
      }
      __builtin_amdgcn_s_setprio(1);
#pragma unroll
      for (int mi = 0; mi < 2; mi++)
#pragma unroll
        for (int ni = 0; ni < 8; ni++)
          acc[mi][ni] = __builtin_amdgcn_mfma_f32_16x16x32_bf16(af[mi], bfr[ni], acc[mi][ni], 0, 0, 0);
      __builtin_amdgcn_s_setprio(0);
    }
    __syncthreads();
  }
}

// ---------------- merged projection GEMM (q/k/v/ipk epilogues) ----------------
// projmap 4-bit codes: 0=q (norm+rope+scale, dual out), 1=k (norm+rope),
//          2=v (transposed out), 3=k-no-rope (norm only)
__global__ __launch_bounds__(256)
void gemm_proj_kernel(const bf16* __restrict__ A, const bf16* __restrict__ Wt,
                      int M, int K, int projmap,
                      const float* __restrict__ b0, const float* __restrict__ b1,
                      const float* __restrict__ b2,
                      const float* __restrict__ rcos, const float* __restrict__ rsin,
                      int pos_off, int tok_off, int Sout,
                      unsigned short* __restrict__ qa_p, const float* __restrict__ nq,
                      unsigned short* __restrict__ ipq_p, const float* __restrict__ nipq, int Sip,
                      unsigned short* __restrict__ ka_p, const float* __restrict__ nk,
                      unsigned short* __restrict__ va_p) {
  __shared__ __align__(16) bf16 Alds[2][128 * 64];
  __shared__ __align__(16) bf16 Blds[2][128 * 64];
  bf16* VtS = Alds[0];   // V^T epilogue staging aliases Alds[0] (dead after K-loop)
  int t = threadIdx.x;
  int lane = t & 63, wid = t >> 6;
  int l16 = lane & 15, lg = lane >> 4;
  int bx, by;
  SWZ_BLOCK(bx, by);
  int bm = bx * 128;
  int proj = by / 24, head = by % 24;
  int code = (projmap >> (proj * 4)) & 15;
  int arow = t >> 3;
  int aseg = (t & 7) ^ (arow & 7);

  f32x4 acc[2][8];
#pragma unroll
  for (int i = 0; i < 2; i++)
#pragma unroll
    for (int j = 0; j < 8; j++) { acc[i][j][0]=0.f; acc[i][j][1]=0.f; acc[i][j][2]=0.f; acc[i][j][3]=0.f; }

  const bf16* Ab = A  + (size_t)(bm + arow) * K + aseg * 8;
  const bf16* Bb = Wt + (size_t)(by * 128 + arow) * K + aseg * 8;
  gemm_core64_db(Ab, Bb, K, Alds, Blds, t, wid, l16, lg, acc);

  const float* bias = proj == 0 ? b0 : (proj == 1 ? b1 : b2);
  int bcol = head * 128;

  if (code == 2) {
    // ---- V: transpose through LDS, coalesced V^T stores (permuted-d rows) ----
#pragma unroll
    for (int half = 0; half < 2; half++) {
      __syncthreads();
#pragma unroll
      for (int mi = 0; mi < 2; mi++)
#pragma unroll
        for (int j = 0; j < 4; j++) {
          int tok = wid * 32 + mi * 16 + lg * 4 + j;
#pragma unroll
          for (int ni = 0; ni < 4; ni++) {
            int rc = l16 * 4 + ni;     // compact row; stored s = l16*8 + ni + 4*half
            float val = acc[mi][ni + 4 * half][j] + bias[bcol + l16 + 16 * (ni + 4 * half)];
            unsigned short uv = f2bf(val);
            VtS[rc * 128 + (tok ^ ((rc & 15) << 3))] = *(bf16*)&uv;
          }
        }
      __syncthreads();
      int rc = t >> 2;                 // 0..63
      int tokbase = (t & 3) * 32;
      int s = (rc >> 2) * 8 + (rc & 3) + 4 * half;   // stored (permuted) d-row
#pragma unroll
      for (int it = 0; it < 4; it++) {
        int tok0 = tokbase + it * 8;
        short8 vv = *reinterpret_cast<const short8*>(&VtS[rc * 128 + (tok0 ^ ((rc & 15) << 3))]);
        *reinterpret_cast<short8*>(
            &va_p[((size_t)head * HD_ + s) * Sout + tok_off + bm + tok0]) = vv;
      }
    }
    return;
  }

  // ---- q / k / ipk epilogues (RMS + optional RoPE/scale), permuted-d short8 stores ----
#pragma unroll
  for (int mi = 0; mi < 2; mi++) {
#pragma unroll
    for (int j = 0; j < 4; j++) {
      int rloc = wid * 32 + mi * 16 + lg * 4 + j;
      int row  = bm + rloc;
      float v[8];
#pragma unroll
      for (int ni = 0; ni < 8; ni++)
        v[ni] = acc[mi][ni][j] + bias[bcol + l16 + 16 * ni];

      float ss = 0.f;
#pragma unroll
      for (int ni = 0; ni < 8; ni++) ss += v[ni] * v[ni];
#pragma unroll
      for (int off = 1; off < 16; off <<= 1) ss += __shfl_xor(ss, off);
      float rr = rsqrtf(ss * (1.f / 128.f) + 1e-6f);

      auto emit = [&](unsigned short* outp, const float* nw, int rope, int scale,
                      int toff, int So) {
        float y[8];
#pragma unroll
        for (int ni = 0; ni < 8; ni++) {
          int col = l16 + 16 * ni;
          y[ni] = v[ni] * rr * nw[col];
        }
        if (rope) {
#pragma unroll
          for (int ni = 0; ni < 8; ni++) {
            int col = l16 + 16 * ni;
            float c  = rcos[(size_t)(pos_off + row) * HD_ + col];
            float sn = rsin[(size_t)(pos_off + row) * HD_ + col];
            float partner = __shfl_xor(y[ni], 1);
            y[ni] = y[ni] * c + ((col & 1) ? partner : -partner) * sn;
          }
        }
        if (scale) {
#pragma unroll
          for (int ni = 0; ni < 8; ni++) y[ni] *= QSCALE_;
        }
        uint4v pk;
        pk[0] = cvtpk(y[0], y[1]); pk[1] = cvtpk(y[2], y[3]);
        pk[2] = cvtpk(y[4], y[5]); pk[3] = cvtpk(y[6], y[7]);
        *reinterpret_cast<uint4v*>(&outp[((size_t)head * So + toff + row) * HD_ + l16 * 8]) = pk;
      };

      if (code == 0) {
        emit(qa_p, nq, 1, 1, tok_off, Sout);
        if (ipq_p) emit(ipq_p, nipq, 0, 1, 0, Sip);
      } else if (code == 1) {
        emit(ka_p, nk, 1, 0, tok_off, Sout);
      } else {  // code 3: ipk
        emit(ka_p, nk, 0, 0, tok_off, Sout);
      }
    }
  }
}

// ---------------- merged output GEMM: img (bx<16) and enc (bx>=16) ----------------
__global__ __launch_bounds__(256)
void gemm_out2_kernel(const bf16* __restrict__ A_img, const bf16* __restrict__ A_enc,
                      const bf16* __restrict__ Wt,
                      const float* __restrict__ bo, const float* __restrict__ bao,
                      float* __restrict__ C_img, float* __restrict__ C_enc) {
  __shared__ __align__(16) bf16 Alds[2][128 * 64];
  __shared__ __align__(16) bf16 Blds[2][128 * 64];
  int t = threadIdx.x;
  int lane = t & 63, wid = t >> 6;
  int l16 = lane & 15, lg = lane >> 4;
  int bx, byn;
  SWZ_BLOCK(bx, byn);
  int is_enc = bx >= 16;
  const bf16* A = is_enc ? A_enc : A_img;
  const bf16* W = Wt + (is_enc ? (size_t)D_ * D_ : 0);
  const float* bias = is_enc ? bao : bo;
  float* C = is_enc ? C_enc : C_img;
  int bm = (is_enc ? bx - 16 : bx) * 128;
  int bn = byn * 128;
  int arow = t >> 3;
  int aseg = (t & 7) ^ (arow & 7);
  const int K = D_;

  f32x4 acc[2][8];
#pragma unroll
  for (int i = 0; i < 2; i++)
#pragma unroll
    for (int j = 0; j < 8; j++) { acc[i][j][0]=0.f; acc[i][j][1]=0.f; acc[i][j][2]=0.f; acc[i][j][3]=0.f; }

  const bf16* Ab = A + (size_t)(bm + arow) * K + aseg * 8;
  const bf16* Bb = W + (size_t)(bn + arow) * K + aseg * 8;
  gemm_core64_db(Ab, Bb, K, Alds, Blds, t, wid, l16, lg, acc);

#pragma unroll
  for (int mi = 0; mi < 2; mi++)
#pragma unroll
    for (int j = 0; j < 4; j++) {
      int row = bm + wid * 32 + mi * 16 + lg * 4 + j;
#pragma unroll
      for (int ni = 0; ni < 8; ni++)
        C[(size_t)row * D_ + bn + l16 + 16 * ni] = acc[mi][ni][j] + bias[bn + l16 + 16 * ni];
    }
}

// ---------------- 2-phase merged flash attention ----------------
// Double-buffered K/V (gload_lds, pre-swizzled source), private P buffer (no alias),
// ONE barrier per KV tile. LPT: long main-attn blocks first, then ip blocks.
__global__ __launch_bounds__(256)
void attn_kernel(const bf16* __restrict__ Q1, const bf16* __restrict__ K1,
                 const bf16* __restrict__ Vt1, unsigned short* __restrict__ O1,
                 int Sq1, int Skv1, int nx1,
                 const bf16* __restrict__ Q2, const bf16* __restrict__ K2,
                 const bf16* __restrict__ Vt2, unsigned short* __restrict__ O2,
                 int Sq2, int Skv2) {
  __shared__ __align__(16) bf16 Kl[2][64 * 128];
  __shared__ __align__(16) bf16 Vl[2][128 * 64];
  __shared__ __align__(16) bf16 Pl[4][2][16 * 64];
  int t = threadIdx.x, lane = t & 63, wid = t >> 6;
  int l16 = lane & 15, lg = lane >> 4;

  // LPT + per-segment XCD swizzle (main: nx1*24 blocks first; ip after)
  int hw = blockIdx.x + blockIdx.y * gridDim.x;
  int n1 = nx1 * 24;
  int is2, bx, h;
  if (hw < n1) {
    int lid = (hw & 7) * (n1 >> 3) + (hw >> 3);
    bx = lid % nx1; h = lid / nx1; is2 = 0;
  } else {
    int hw2 = hw - n1;
    int n2 = gridDim.x * gridDim.y - n1;
    int lid = (hw2 & 7) * (n2 >> 3) + (hw2 >> 3);
    bx = lid % 16; h = lid / 16; is2 = 1;
  }
  const bf16* Q  = is2 ? Q2  : Q1;
  const bf16* K  = is2 ? K2  : K1;
  const bf16* Vt = is2 ? Vt2 : Vt1;
  unsigned short* O = is2 ? O2 : O1;
  int Sq  = is2 ? Sq2  : Sq1;
  int Skv = is2 ? Skv2 : Skv1;
  int qb = bx * 128 + wid * 32;

  const bf16* Qh  = Q  + (size_t)h * Sq * HD_;
  const bf16* Kh  = K  + (size_t)h * Skv * HD_;
  const bf16* Vth = Vt + (size_t)h * HD_ * Skv;

  bf16x8 qf[2][4];
#pragma unroll
  for (int m = 0; m < 2; m++)
#pragma unroll
    for (int kb = 0; kb < 4; kb++)
      qf[m][kb] = *reinterpret_cast<const bf16x8*>(
          &Qh[(size_t)(qb + m * 16 + l16) * HD_ + lg * 8 + kb * 32]);

  f32x4 acc[2][8];
#pragma unroll
  for (int m = 0; m < 2; m++)
#pragma unroll
    for (int cb = 0; cb < 8; cb++) { acc[m][cb][0]=0.f; acc[m][cb][1]=0.f; acc[m][cb][2]=0.f; acc[m][cb][3]=0.f; }
  float l_r[2] = {0.f, 0.f};

  auto STAGE = [&](int b, int kt) {
    char* KlB = (char*)Kl[b] + t * 16;
    char* VlB = (char*)Vl[b] + t * 16;
#pragma unroll
    for (int p = 0; p < 4; p++) {
      int rk = p * 16 + (t >> 4);
      int sk = (t & 15) ^ (rk & 7);
      gload16(Kh + (size_t)(kt + rk) * HD_ + sk * 8, KlB + p * 4096);
      int rv = p * 32 + (t >> 3);
      int sv = (t & 7) ^ (rv & 7);
      gload16(Vth + (size_t)rv * Skv + kt + sv * 8, VlB + p * 4096);
    }
  };

  int nt = Skv >> 6;
  STAGE(0, 0);
  __syncthreads();

  for (int ti = 0; ti < nt; ti++) {
    int b = ti & 1;
    if (ti + 1 < nt) STAGE(b ^ 1, (ti + 1) * 64);

    f32x4 sc[2][4];
#pragma unroll
    for (int m = 0; m < 2; m++)
#pragma unroll
      for (int nb = 0; nb < 4; nb++) { sc[m][nb][0]=0.f; sc[m][nb][1]=0.f; sc[m][nb][2]=0.f; sc[m][nb][3]=0.f; }
    __builtin_amdgcn_s_setprio(1);
#pragma unroll
    for (int kb = 0; kb < 4; kb++) {
#pragma unroll
      for (int nb = 0; nb < 4; nb++) {
        int r = nb * 16 + l16;
        bf16x8 kf = *reinterpret_cast<const bf16x8*>(
            (char*)Kl[b] + r * 256 + ((lg * 16 + kb * 64) ^ ((r & 7) << 4)));
        sc[0][nb] = __builtin_amdgcn_mfma_f32_16x16x32_bf16(kf, qf[0][kb], sc[0][nb], 0, 0, 0);
        sc[1][nb] = __builtin_amdgcn_mfma_f32_16x16x32_bf16(kf, qf[1][kb], sc[1][nb], 0, 0, 0);
      }
    }
    __builtin_amdgcn_s_setprio(0);

#pragma unroll
    for (int m = 0; m < 2; m++) {
      float part = 0.f;
#pragma unroll
      for (int nb = 0; nb < 4; nb++)
#pragma unroll
        for (int j = 0; j < 4; j++) {
          float p = exp2f(sc[m][nb][j]);
          sc[m][nb][j] = p;
          part += p;
        }
      l_r[m] += part;
      char* Pb = (char*)&Pl[wid][m][0] + l16 * 128;
#pragma unroll
      for (int nb = 0; nb < 4; nb++) {
#pragma unroll
        for (int w = 0; w < 2; w++) {
          unsigned int pk = cvtpk(sc[m][nb][2 * w], sc[m][nb][2 * w + 1]);
          int colb = nb * 32 + lg * 8 + w * 4;
          *(unsigned int*)(Pb + (colb ^ ((l16 & 7) << 4))) = pk;
        }
      }
    }
    asm volatile("s_waitcnt lgkmcnt(0)" ::: "memory");

#pragma unroll
    for (int kb2 = 0; kb2 < 2; kb2++) {
      bf16x8 pa[2];
#pragma unroll
      for (int m = 0; m < 2; m++)
        pa[m] = *reinterpret_cast<const bf16x8*>(
            (char*)&Pl[wid][m][0] + l16 * 128 + ((lg * 16 + kb2 * 64) ^ ((l16 & 7) << 4)));
      __builtin_amdgcn_s_setprio(1);
#pragma unroll
      for (int cb = 0; cb < 8; cb++) {
        int d = cb * 16 + l16;
        bf16x8 vf = *reinterpret_cast<const bf16x8*>(
            (char*)Vl[b] + d * 128 + ((lg * 16 + kb2 * 64) ^ ((d & 7) << 4)));
        acc[0][cb] = __builtin_amdgcn_mfma_f32_16x16x32_bf16(pa[0], vf, acc[0][cb], 0, 0, 0);
        acc[1][cb] = __builtin_amdgcn_mfma_f32_16x16x32_bf16(pa[1], vf, acc[1][cb], 0, 0, 0);
      }
      __builtin_amdgcn_s_setprio(0);
    }
    __syncthreads();
  }

#pragma unroll
  for (int m = 0; m < 2; m++) {
    l_r[m] += __shfl_xor(l_r[m], 16);
    l_r[m] += __shfl_xor(l_r[m], 32);
  }

#pragma unroll
  for (int m = 0; m < 2; m++) {
    float inv[4];
#pragma unroll
    for (int j = 0; j < 4; j++) inv[j] = 1.0f / __shfl(l_r[m], lg * 4 + j);
#pragma unroll
    for (int cb = 0; cb < 8; cb++) {
      int col = h * HD_ + (l16 & 7) * 16 + cb * 2 + (l16 >> 3);
#pragma unroll
      for (int j = 0; j < 4; j++) {
        int row = qb + m * 16 + lg * 4 + j;
        O[(size_t)row * (H_ * HD_) + col] = f2bf(acc[m][cb][j] * inv[j]);
      }
    }
  }
}

// ---------------- combine (img rows only): img_in = bf16(attn[512+r] + ip_out[r]) -------
__global__ void combine_kernel(const unsigned short* __restrict__ attn,
                               const unsigned short* __restrict__ ipo,
                               unsigned short* __restrict__ img_in) {
  size_t i = ((size_t)blockIdx.x * blockDim.x + threadIdx.x) * 8;
  if (i >= (size_t)SIMG_ * D_) return;
  short8 a = *reinterpret_cast<const short8*>(attn + (size_t)LTXT_ * D_ + i);
  short8 b = *reinterpret_cast<const short8*>(ipo + i);
  short8 o;
#pragma unroll
  for (int j = 0; j < 8; j++)
    o[j] = (short)f2bf(bf2f((unsigned short)a[j]) + bf2f((unsigned short)b[j]));
  *reinterpret_cast<short8*>(img_in + i) = o;
}

extern "C" void kernel_launch(void* const* d_in, const int* in_sizes, int n_in,
                              void* d_out, int out_size, void* d_ws, size_t ws_size,
                              hipStream_t stream) {
  const float* hs   = (const float*)d_in[0];
  const float* ehs  = (const float*)d_in[1];
  const float* iphs = (const float*)d_in[2];
  const float* rcos = (const float*)d_in[3];
  const float* rsin = (const float*)d_in[4];
  const float* Wq   = (const float*)d_in[5];  const float* bq   = (const float*)d_in[6];
  const float* Wk   = (const float*)d_in[7];  const float* bk   = (const float*)d_in[8];
  const float* Wv   = (const float*)d_in[9];  const float* bv   = (const float*)d_in[10];
  const float* nqw  = (const float*)d_in[11]; const float* nkw  = (const float*)d_in[12];
  const float* aWq  = (const float*)d_in[13]; const float* abq  = (const float*)d_in[14];
  const float* aWk  = (const float*)d_in[15]; const float* abk  = (const float*)d_in[16];
  const float* aWv  = (const float*)d_in[17]; const float* abv  = (const float*)d_in[18];
  const float* naqw = (const float*)d_in[19]; const float* nakw = (const float*)d_in[20];
  const float* Wkip = (const float*)d_in[21]; const float* bkip = (const float*)d_in[22];
  const float* Wvip = (const float*)d_in[23]; const float* bvip = (const float*)d_in[24];
  const float* nipqw= (const float*)d_in[25]; const float* nipkw= (const float*)d_in[26];
  const float* Wo   = (const float*)d_in[27]; const float* bo   = (const float*)d_in[28];
  const float* Wao  = (const float*)d_in[29]; const float* bao  = (const float*)d_in[30];
  float* out_img = (float*)d_out;
  float* out_enc = out_img + (size_t)SIMG_ * D_;

  // ---- workspace layout (total 141,557,760 B) ----
  char* ws = (char*)d_ws;
  bf16*  Wt      = (bf16*)(ws + 0);                    // 3 slabs x 18,874,368
  unsigned short* attn_bf   = (unsigned short*)(ws + 37748736);   // 15,728,640 (overlay slab2)
  bf16*  qa      = (bf16*)(ws + 56623104);             // 15,728,640
  bf16*  ka      = (bf16*)(ws + 72351744);             // 15,728,640
  bf16*  vaT     = (bf16*)(ws + 88080384);             // 15,728,640  [24][128][2560]
  bf16*  ipq_bf  = (bf16*)(ws + 103809024);            // 12,582,912
  bf16*  ipk_bf  = (bf16*)(ws + 116391936);            //  6,291,456
  bf16*  ipvT   = (bf16*)(ws + 122683392);             //  6,291,456  [24][128][1024]
  bf16*  act_bf  = (bf16*)(ws + 128974848);            // 12,582,912  (hs cast; later enc+ip casts)
  bf16*  enc_bf  = act_bf;                             // first 3,145,728
  bf16*  ip_bf   = act_bf + (size_t)LTXT_ * D_;        // next 4,194,304
  unsigned short* ip_out_bf = (unsigned short*)act_bf; // overlay (dead after ip GEMM)
  bf16*  img_in  = (bf16*)qa;                          // overlay qa (dead after attn)
  if (ws_size < 141557760) return;

  dim3 tb2(16, 32);

  // 1) hs cast + QKV weights transpose + merged QKV GEMM
  cast_kernel<<<SIMG_ * D_ / 4 / 256, 256, 0, stream>>>(hs, (unsigned short*)act_bf, SIMG_ * D_ / 4);
  transpose_cast3_kernel<<<dim3(48, 48, 3), tb2, 0, stream>>>(Wq, Wk, Wv, (unsigned short*)Wt, D_, D_);
  gemm_proj_kernel<<<dim3(16, 72), 256, 0, stream>>>(act_bf, Wt, SIMG_, D_, 0x210,
      bq, bk, bv, rcos, rsin, LTXT_, LTXT_, SALL_,
      (unsigned short*)qa, nqw, (unsigned short*)ipq_bf, nipqw, SIMG_,
      (unsigned short*)ka, nkw, (unsigned short*)vaT);

  // 2) enc + ip casts in one dispatch (act_bf region; hs_bf dead now)
  cast2_kernel<<<(LTXT_ * D_ / 4 + NIP_ * IPD_ / 4 + 255) / 256, 256, 0, stream>>>(
      ehs,  (unsigned short*)enc_bf, LTXT_ * D_ / 4,
      iphs, (unsigned short*)ip_bf,  NIP_ * IPD_ / 4);

  // 3) enc weights + merged enc GEMM
  transpose_cast3_kernel<<<dim3(48, 48, 3), tb2, 0, stream>>>(aWq, aWk, aWv, (unsigned short*)Wt, D_, D_);
  gemm_proj_kernel<<<dim3(4, 72), 256, 0, stream>>>(enc_bf, Wt, LTXT_, D_, 0x210,
      abq, abk, abv, rcos, rsin, 0, 0, SALL_,
      (unsigned short*)qa, naqw, nullptr, nipqw, SIMG_,
      (unsigned short*)ka, nakw, (unsigned short*)vaT);

  // 4) ip weights + merged ip-KV GEMM
  transpose_cast3_kernel<<<dim3(48, 32, 2), tb2, 0, stream>>>(Wkip, Wvip, Wvip, (unsigned short*)Wt, IPD_, D_);
  gemm_proj_kernel<<<dim3(8, 48), 256, 0, stream>>>(ip_bf, Wt, NIP_, IPD_, 0x23,
      bkip, bvip, bvip, nullptr, nullptr, 0, 0, NIP_,
      nullptr, nullptr, nullptr, nullptr, 0,
      (unsigned short*)ipk_bf, nipkw, (unsigned short*)ipvT);

  // 5) Wo + Wao transpose into slabs 0,1 (act_bf now dead -> ip_out_bf overlay OK)
  transpose_cast3_kernel<<<dim3(48, 48, 2), tb2, 0, stream>>>(Wo, Wao, Wao, (unsigned short*)Wt, D_, D_);

  // 6) both attentions in ONE dispatch (864 blocks, LPT: main first)
  attn_kernel<<<dim3(SALL_ / 128 + SIMG_ / 128, H_), 256, 0, stream>>>(
      qa, ka, vaT, attn_bf, SALL_, SALL_, SALL_ / 128,
      ipq_bf, ipk_bf, ipvT, ip_out_bf, SIMG_, NIP_);

  // 7) combine img rows (enc rows feed Wao GEMM directly from attn_bf)
  combine_kernel<<<SIMG_ * D_ / 8 / 256, 256, 0, stream>>>(attn_bf, ip_out_bf, (unsigned short*)img_in);

  // 8) merged output projections (img + enc in one dispatch)
  gemm_out2_kernel<<<dim3(20, 24), 256, 0, stream>>>(img_in, (const bf16*)attn_bf, Wt,
                                                     bo, bao, out_img, out_enc);
}

// Round 18
// 609.563 us; speedup vs baseline: 1.0289x; 1.0289x over previous
//
#include <hip/hip_runtime.h>
#include <hip/hip_bf16.h>
#include <cmath>
#include <cstdint>

#define H_    24
#define HD_   128
#define D_    3072
#define SIMG_ 2048
#define LTXT_ 512
#define SALL_ 2560
#define NIP_  1024
#define IPD_  2048

using bf16 = __hip_bfloat16;
typedef __bf16 bf16x8 __attribute__((ext_vector_type(8)));
typedef float  f32x4  __attribute__((ext_vector_type(4)));
typedef short  short8 __attribute__((ext_vector_type(8)));
typedef unsigned int uint4v __attribute__((ext_vector_type(4)));

// 1/sqrt(128) * log2(e)  (exp2-domain softmax)
#define QSCALE_ 0.12751741f

// XCD-aware bijective block swizzle (requires gridX*gridY % 8 == 0)
#define SWZ_BLOCK(bx, by)                                              \
  {                                                                    \
    int _gx = gridDim.x;                                               \
    int _hw = blockIdx.x + blockIdx.y * _gx;                           \
    int _n  = _gx * gridDim.y;                                         \
    int _lid = (_hw & 7) * (_n >> 3) + (_hw >> 3);                     \
    bx = _lid % _gx;                                                   \
    by = _lid / _gx;                                                   \
  }

__device__ __forceinline__ unsigned short f2bf(float f) {
  unsigned int u = __float_as_uint(f);
  unsigned int r = (u + 0x7fffu + ((u >> 16) & 1u)) >> 16;   // RNE
  return (unsigned short)r;
}
__device__ __forceinline__ float bf2f(unsigned short u) {
  return __uint_as_float(((unsigned int)u) << 16);
}
__device__ __forceinline__ unsigned int cvtpk(float lo, float hi) {
  unsigned int pk;
  asm("v_cvt_pk_bf16_f32 %0, %1, %2" : "=v"(pk) : "v"(lo), "v"(hi));
  return pk;
}

__device__ __forceinline__ void gload16(const void* g, void* l) {
  __builtin_amdgcn_global_load_lds(
      (const __attribute__((address_space(1))) unsigned*)g,
      (__attribute__((address_space(3))) unsigned*)l, 16, 0, 0);
}

// NOTE: q/k/V^T head-dim is stored PERMUTED: stored position s of original col c is
// s = (c&15)*8 + (c>>4).  Dot products over d are permutation-invariant; the
// attention O-write maps back to original order.

// ---------------- elementwise cast fp32 -> bf16 ----------------
__global__ void cast_kernel(const float* __restrict__ x, unsigned short* __restrict__ y, int n4) {
  int i = blockIdx.x * blockDim.x + threadIdx.x;
  if (i >= n4) return;
  float4 v = reinterpret_cast<const float4*>(x)[i];
  ushort4 o = make_ushort4(f2bf(v.x), f2bf(v.y), f2bf(v.z), f2bf(v.w));
  reinterpret_cast<ushort4*>(y)[i] = o;
}

// ---------------- dual cast fp32 -> bf16 (two tensors in one dispatch) ----------------
__global__ void cast2_kernel(const float* __restrict__ x1, unsigned short* __restrict__ y1, int n4_1,
                             const float* __restrict__ x2, unsigned short* __restrict__ y2, int n4_2) {
  int i = blockIdx.x * blockDim.x + threadIdx.x;
  const float* x; unsigned short* y;
  if (i < n4_1) { x = x1; y = y1; }
  else { i -= n4_1; if (i >= n4_2) return; x = x2; y = y2; }
  float4 v = reinterpret_cast<const float4*>(x)[i];
  ushort4 o = make_ushort4(f2bf(v.x), f2bf(v.y), f2bf(v.z), f2bf(v.w));
  reinterpret_cast<ushort4*>(y)[i] = o;
}

// ------- transpose + cast (up to 3 weights): W[R][C] f32 -> Wt slab z: [C][R] bf16 -------
__global__ __launch_bounds__(512)
void transpose_cast3_kernel(const float* __restrict__ W0, const float* __restrict__ W1,
                            const float* __restrict__ W2, unsigned short* __restrict__ Wt,
                            int R, int C) {
  __shared__ float tile[64][69];
  const float* W = blockIdx.z == 0 ? W0 : (blockIdx.z == 1 ? W1 : W2);
  unsigned short* dst = Wt + (size_t)blockIdx.z * R * C;
  int bx = blockIdx.x * 64, by = blockIdx.y * 64;
  int tx = threadIdx.x, ty = threadIdx.y;   // (16, 32)
#pragma unroll
  for (int i = 0; i < 2; i++) {
    int r = ty + 32 * i;
    float4 v = *reinterpret_cast<const float4*>(&W[(size_t)(by + r) * C + bx + tx * 4]);
    tile[r][tx * 4 + 0] = v.x; tile[r][tx * 4 + 1] = v.y;
    tile[r][tx * 4 + 2] = v.z; tile[r][tx * 4 + 3] = v.w;
  }
  __syncthreads();
  int tid = ty * 16 + tx;
  int c = tid >> 3, r0 = (tid & 7) * 8;
  short8 o;
#pragma unroll
  for (int j = 0; j < 8; j++) o[j] = (short)f2bf(tile[r0 + j][c]);
  *reinterpret_cast<short8*>(&dst[(size_t)(bx + c) * R + by + r0]) = o;
}

// ---------------- 2-phase GEMM core: 128x128 tile, BK=64, double-buffered LDS ----------
// LDS content: L[row][seg] = G[row][seg ^ (row&7)] (16B segs); reads XOR the same mask.
// Per iter: issue STAGE(next) first, compute current, single barrier (drains vmcnt).
__device__ __forceinline__ void gemm_core64_db(const bf16* __restrict__ Ab,
                                               const bf16* __restrict__ Bb, int K,
                                               bf16 (*Alds)[128 * 64], bf16 (*Blds)[128 * 64],
                                               int t, int wid, int l16, int lg,
                                               f32x4 (&acc)[2][8]) {
  auto stage = [&](int b, int kt) {
    char* AldsB = (char*)Alds[b] + t * 16;
    char* BldsB = (char*)Blds[b] + t * 16;
#pragma unroll
    for (int p = 0; p < 4; p++) {
      gload16(Ab + (size_t)(32 * p) * K + kt, AldsB + p * 4096);
      gload16(Bb + (size_t)(32 * p) * K + kt, BldsB + p * 4096);
    }
  };
  int nk = K >> 6;
  stage(0, 0);
  __syncthreads();
  for (int i = 0; i < nk; i++) {
    int b = i & 1;
    if (i + 1 < nk) stage(b ^ 1, (i + 1) << 6);
#pragma unroll
    for (int kb = 0; kb < 2; kb++) {
      bf16x8 af[2], bfr[8];
#pragma unroll
      for (int mi = 0; mi < 2; mi++) {
        int r = wid * 32 + mi * 16 + l16;
        af[mi] = *reinterpret_cast<const bf16x8*>(
            (char*)Alds[b] + r * 128 + ((lg * 16 + kb * 64) ^ ((r & 7) << 4)));
      }
#pragma unroll
      for (int ni = 0; ni < 8; ni++) {
        int r = ni * 16 + l16;
        bfr[ni] = *reinterpret_cast<const bf16x8*>(
            (char*)Blds[b] + r * 128 + ((lg * 16 + kb * 64) ^ ((r & 7) << 4)));
      }
      __builtin_amdgcn_s_setprio(1);
#pragma unroll
      for (int mi = 0; mi < 2; mi++)
#pragma unroll
        for (int ni = 0; ni < 8; ni++)
          acc[mi][ni] = __builtin_amdgcn_mfma_f32_16x16x32_bf16(af[mi], bfr[ni], acc[mi][ni], 0, 0, 0);
      __builtin_amdgcn_s_setprio(0);
    }
    __syncthreads();
  }
}

// ---------------- merged projection GEMM (q/k/v/ipk epilogues) ----------------
// projmap 4-bit codes: 0=q (norm+rope+scale, dual out), 1=k (norm+rope),
//          2=v (transposed out), 3=k-no-rope (norm only)
__global__ __launch_bounds__(256)
void gemm_proj_kernel(const bf16* __restrict__ A, const bf16* __restrict__ Wt,
                      int M, int K, int projmap,
                      const float* __restrict__ b0, const float* __restrict__ b1,
                      const float* __restrict__ b2,
                      const float* __restrict__ rcos, const float* __restrict__ rsin,
                      int pos_off, int tok_off, int Sout,
                      unsigned short* __restrict__ qa_p, const float* __restrict__ nq,
                      unsigned short* __restrict__ ipq_p, const float* __restrict__ nipq, int Sip,
                      unsigned short* __restrict__ ka_p, const float* __restrict__ nk,
                      unsigned short* __restrict__ va_p) {
  __shared__ __align__(16) bf16 Alds[2][128 * 64];
  __shared__ __align__(16) bf16 Blds[2][128 * 64];
  bf16* VtS = Alds[0];   // V^T epilogue staging aliases Alds[0] (dead after K-loop)
  int t = threadIdx.x;
  int lane = t & 63, wid = t >> 6;
  int l16 = lane & 15, lg = lane >> 4;
  int bx, by;
  SWZ_BLOCK(bx, by);
  int bm = bx * 128;
  int proj = by / 24, head = by % 24;
  int code = (projmap >> (proj * 4)) & 15;
  int arow = t >> 3;
  int aseg = (t & 7) ^ (arow & 7);

  f32x4 acc[2][8];
#pragma unroll
  for (int i = 0; i < 2; i++)
#pragma unroll
    for (int j = 0; j < 8; j++) { acc[i][j][0]=0.f; acc[i][j][1]=0.f; acc[i][j][2]=0.f; acc[i][j][3]=0.f; }

  const bf16* Ab = A  + (size_t)(bm + arow) * K + aseg * 8;
  const bf16* Bb = Wt + (size_t)(by * 128 + arow) * K + aseg * 8;
  gemm_core64_db(Ab, Bb, K, Alds, Blds, t, wid, l16, lg, acc);

  const float* bias = proj == 0 ? b0 : (proj == 1 ? b1 : b2);
  int bcol = head * 128;

  if (code == 2) {
    // ---- V: transpose through LDS, coalesced V^T stores (permuted-d rows) ----
#pragma unroll
    for (int half = 0; half < 2; half++) {
      __syncthreads();
#pragma unroll
      for (int mi = 0; mi < 2; mi++)
#pragma unroll
        for (int j = 0; j < 4; j++) {
          int tok = wid * 32 + mi * 16 + lg * 4 + j;
#pragma unroll
          for (int ni = 0; ni < 4; ni++) {
            int rc = l16 * 4 + ni;     // compact row; stored s = l16*8 + ni + 4*half
            float val = acc[mi][ni + 4 * half][j] + bias[bcol + l16 + 16 * (ni + 4 * half)];
            unsigned short uv = f2bf(val);
            VtS[rc * 128 + (tok ^ ((rc & 15) << 3))] = *(bf16*)&uv;
          }
        }
      __syncthreads();
      int rc = t >> 2;                 // 0..63
      int tokbase = (t & 3) * 32;
      int s = (rc >> 2) * 8 + (rc & 3) + 4 * half;   // stored (permuted) d-row
#pragma unroll
      for (int it = 0; it < 4; it++) {
        int tok0 = tokbase + it * 8;
        short8 vv = *reinterpret_cast<const short8*>(&VtS[rc * 128 + (tok0 ^ ((rc & 15) << 3))]);
        *reinterpret_cast<short8*>(
            &va_p[((size_t)head * HD_ + s) * Sout + tok_off + bm + tok0]) = vv;
      }
    }
    return;
  }

  // ---- q / k / ipk epilogues (RMS + optional RoPE/scale), permuted-d short8 stores ----
#pragma unroll
  for (int mi = 0; mi < 2; mi++) {
#pragma unroll
    for (int j = 0; j < 4; j++) {
      int rloc = wid * 32 + mi * 16 + lg * 4 + j;
      int row  = bm + rloc;
      float v[8];
#pragma unroll
      for (int ni = 0; ni < 8; ni++)
        v[ni] = acc[mi][ni][j] + bias[bcol + l16 + 16 * ni];

      float ss = 0.f;
#pragma unroll
      for (int ni = 0; ni < 8; ni++) ss += v[ni] * v[ni];
#pragma unroll
      for (int off = 1; off < 16; off <<= 1) ss += __shfl_xor(ss, off);
      float rr = rsqrtf(ss * (1.f / 128.f) + 1e-6f);

      auto emit = [&](unsigned short* outp, const float* nw, int rope, int scale,
                      int toff, int So) {
        float y[8];
#pragma unroll
        for (int ni = 0; ni < 8; ni++) {
          int col = l16 + 16 * ni;
          y[ni] = v[ni] * rr * nw[col];
        }
        if (rope) {
#pragma unroll
          for (int ni = 0; ni < 8; ni++) {
            int col = l16 + 16 * ni;
            float c  = rcos[(size_t)(pos_off + row) * HD_ + col];
            float sn = rsin[(size_t)(pos_off + row) * HD_ + col];
            float partner = __shfl_xor(y[ni], 1);
            y[ni] = y[ni] * c + ((col & 1) ? partner : -partner) * sn;
          }
        }
        if (scale) {
#pragma unroll
          for (int ni = 0; ni < 8; ni++) y[ni] *= QSCALE_;
        }
        uint4v pk;
        pk[0] = cvtpk(y[0], y[1]); pk[1] = cvtpk(y[2], y[3]);
        pk[2] = cvtpk(y[4], y[5]); pk[3] = cvtpk(y[6], y[7]);
        *reinterpret_cast<uint4v*>(&outp[((size_t)head * So + toff + row) * HD_ + l16 * 8]) = pk;
      };

      if (code == 0) {
        emit(qa_p, nq, 1, 1, tok_off, Sout);
        if (ipq_p) emit(ipq_p, nipq, 0, 1, 0, Sip);
      } else if (code == 1) {
        emit(ka_p, nk, 1, 0, tok_off, Sout);
      } else {  // code 3: ipk
        emit(ka_p, nk, 0, 0, tok_off, Sout);
      }
    }
  }
}

// ---------------- merged output GEMM: img (bx<16) and enc (bx>=16) ----------------
__global__ __launch_bounds__(256)
void gemm_out2_kernel(const bf16* __restrict__ A_img, const bf16* __restrict__ A_enc,
                      const bf16* __restrict__ Wt,
                      const float* __restrict__ bo, const float* __restrict__ bao,
                      float* __restrict__ C_img, float* __restrict__ C_enc) {
  __shared__ __align__(16) bf16 Alds[2][128 * 64];
  __shared__ __align__(16) bf16 Blds[2][128 * 64];
  int t = threadIdx.x;
  int lane = t & 63, wid = t >> 6;
  int l16 = lane & 15, lg = lane >> 4;
  int bx, byn;
  SWZ_BLOCK(bx, byn);
  int is_enc = bx >= 16;
  const bf16* A = is_enc ? A_enc : A_img;
  const bf16* W = Wt + (is_enc ? (size_t)D_ * D_ : 0);
  const float* bias = is_enc ? bao : bo;
  float* C = is_enc ? C_enc : C_img;
  int bm = (is_enc ? bx - 16 : bx) * 128;
  int bn = byn * 128;
  int arow = t >> 3;
  int aseg = (t & 7) ^ (arow & 7);
  const int K = D_;

  f32x4 acc[2][8];
#pragma unroll
  for (int i = 0; i < 2; i++)
#pragma unroll
    for (int j = 0; j < 8; j++) { acc[i][j][0]=0.f; acc[i][j][1]=0.f; acc[i][j][2]=0.f; acc[i][j][3]=0.f; }

  const bf16* Ab = A + (size_t)(bm + arow) * K + aseg * 8;
  const bf16* Bb = W + (size_t)(bn + arow) * K + aseg * 8;
  gemm_core64_db(Ab, Bb, K, Alds, Blds, t, wid, l16, lg, acc);

#pragma unroll
  for (int mi = 0; mi < 2; mi++)
#pragma unroll
    for (int j = 0; j < 4; j++) {
      int row = bm + wid * 32 + mi * 16 + lg * 4 + j;
#pragma unroll
      for (int ni = 0; ni < 8; ni++)
        C[(size_t)row * D_ + bn + l16 + 16 * ni] = acc[mi][ni][j] + bias[bn + l16 + 16 * ni];
    }
}

// ---------------- 2-phase merged flash attention ----------------
// Double-buffered K/V (gload_lds, pre-swizzled source), private P buffer (no alias),
// ONE barrier per KV tile. LPT: long main-attn blocks first, then ip blocks.
__global__ __launch_bounds__(256)
void attn_kernel(const bf16* __restrict__ Q1, const bf16* __restrict__ K1,
                 const bf16* __restrict__ Vt1, unsigned short* __restrict__ O1,
                 int Sq1, int Skv1, int nx1,
                 const bf16* __restrict__ Q2, const bf16* __restrict__ K2,
                 const bf16* __restrict__ Vt2, unsigned short* __restrict__ O2,
                 int Sq2, int Skv2) {
  __shared__ __align__(16) bf16 Kl[2][64 * 128];
  __shared__ __align__(16) bf16 Vl[2][128 * 64];
  __shared__ __align__(16) bf16 Pl[4][2][16 * 64];
  int t = threadIdx.x, lane = t & 63, wid = t >> 6;
  int l16 = lane & 15, lg = lane >> 4;

  // LPT + per-segment XCD swizzle (main: nx1*24 blocks first; ip after)
  int hw = blockIdx.x + blockIdx.y * gridDim.x;
  int n1 = nx1 * 24;
  int is2, bx, h;
  if (hw < n1) {
    int lid = (hw & 7) * (n1 >> 3) + (hw >> 3);
    bx = lid % nx1; h = lid / nx1; is2 = 0;
  } else {
    int hw2 = hw - n1;
    int n2 = gridDim.x * gridDim.y - n1;
    int lid = (hw2 & 7) * (n2 >> 3) + (hw2 >> 3);
    bx = lid % 16; h = lid / 16; is2 = 1;
  }
  const bf16* Q  = is2 ? Q2  : Q1;
  const bf16* K  = is2 ? K2  : K1;
  const bf16* Vt = is2 ? Vt2 : Vt1;
  unsigned short* O = is2 ? O2 : O1;
  int Sq  = is2 ? Sq2  : Sq1;
  int Skv = is2 ? Skv2 : Skv1;
  int qb = bx * 128 + wid * 32;

  const bf16* Qh  = Q  + (size_t)h * Sq * HD_;
  const bf16* Kh  = K  + (size_t)h * Skv * HD_;
  const bf16* Vth = Vt + (size_t)h * HD_ * Skv;

  bf16x8 qf[2][4];
#pragma unroll
  for (int m = 0; m < 2; m++)
#pragma unroll
    for (int kb = 0; kb < 4; kb++)
      qf[m][kb] = *reinterpret_cast<const bf16x8*>(
          &Qh[(size_t)(qb + m * 16 + l16) * HD_ + lg * 8 + kb * 32]);

  f32x4 acc[2][8];
#pragma unroll
  for (int m = 0; m < 2; m++)
#pragma unroll
    for (int cb = 0; cb < 8; cb++) { acc[m][cb][0]=0.f; acc[m][cb][1]=0.f; acc[m][cb][2]=0.f; acc[m][cb][3]=0.f; }
  float l_r[2] = {0.f, 0.f};

  auto STAGE = [&](int b, int kt) {
    char* KlB = (char*)Kl[b] + t * 16;
    char* VlB = (char*)Vl[b] + t * 16;
#pragma unroll
    for (int p = 0; p < 4; p++) {
      int rk = p * 16 + (t >> 4);
      int sk = (t & 15) ^ (rk & 7);
      gload16(Kh + (size_t)(kt + rk) * HD_ + sk * 8, KlB + p * 4096);
      int rv = p * 32 + (t >> 3);
      int sv = (t & 7) ^ (rv & 7);
      gload16(Vth + (size_t)rv * Skv + kt + sv * 8, VlB + p * 4096);
    }
  };

  int nt = Skv >> 6;
  STAGE(0, 0);
  __syncthreads();

  for (int ti = 0; ti < nt; ti++) {
    int b = ti & 1;
    if (ti + 1 < nt) STAGE(b ^ 1, (ti + 1) * 64);

    f32x4 sc[2][4];
#pragma unroll
    for (int m = 0; m < 2; m++)
#pragma unroll
      for (int nb = 0; nb < 4; nb++) { sc[m][nb][0]=0.f; sc[m][nb][1]=0.f; sc[m][nb][2]=0.f; sc[m][nb][3]=0.f; }
    __builtin_amdgcn_s_setprio(1);
#pragma unroll
    for (int kb = 0; kb < 4; kb++) {
#pragma unroll
      for (int nb = 0; nb < 4; nb++) {
        int r = nb * 16 + l16;
        bf16x8 kf = *reinterpret_cast<const bf16x8*>(
            (char*)Kl[b] + r * 256 + ((lg * 16 + kb * 64) ^ ((r & 7) << 4)));
        sc[0][nb] = __builtin_amdgcn_mfma_f32_16x16x32_bf16(kf, qf[0][kb], sc[0][nb], 0, 0, 0);
        sc[1][nb] = __builtin_amdgcn_mfma_f32_16x16x32_bf16(kf, qf[1][kb], sc[1][nb], 0, 0, 0);
      }
    }
    __builtin_amdgcn_s_setprio(0);

#pragma unroll
    for (int m = 0; m < 2; m++) {
      float part = 0.f;
#pragma unroll
      for (int nb = 0; nb < 4; nb++)
#pragma unroll
        for (int j = 0; j < 4; j++) {
          float p = exp2f(sc[m][nb][j]);
          sc[m][nb][j] = p;
          part += p;
        }
      l_r[m] += part;
      char* Pb = (char*)&Pl[wid][m][0] + l16 * 128;
#pragma unroll
      for (int nb = 0; nb < 4; nb++) {
#pragma unroll
        for (int w = 0; w < 2; w++) {
          unsigned int pk = cvtpk(sc[m][nb][2 * w], sc[m][nb][2 * w + 1]);
          int colb = nb * 32 + lg * 8 + w * 4;
          *(unsigned int*)(Pb + (colb ^ ((l16 & 7) << 4))) = pk;
        }
      }
    }
    asm volatile("s_waitcnt lgkmcnt(0)" ::: "memory");

#pragma unroll
    for (int kb2 = 0; kb2 < 2; kb2++) {
      bf16x8 pa[2];
#pragma unroll
      for (int m = 0; m < 2; m++)
        pa[m] = *reinterpret_cast<const bf16x8*>(
            (char*)&Pl[wid][m][0] + l16 * 128 + ((lg * 16 + kb2 * 64) ^ ((l16 & 7) << 4)));
      __builtin_amdgcn_s_setprio(1);
#pragma unroll
      for (int cb = 0; cb < 8; cb++) {
        int d = cb * 16 + l16;
        bf16x8 vf = *reinterpret_cast<const bf16x8*>(
            (char*)Vl[b] + d * 128 + ((lg * 16 + kb2 * 64) ^ ((d & 7) << 4)));
        acc[0][cb] = __builtin_amdgcn_mfma_f32_16x16x32_bf16(pa[0], vf, acc[0][cb], 0, 0, 0);
        acc[1][cb] = __builtin_amdgcn_mfma_f32_16x16x32_bf16(pa[1], vf, acc[1][cb], 0, 0, 0);
      }
      __builtin_amdgcn_s_setprio(0);
    }
    __syncthreads();
  }

#pragma unroll
  for (int m = 0; m < 2; m++) {
    l_r[m] += __shfl_xor(l_r[m], 16);
    l_r[m] += __shfl_xor(l_r[m], 32);
  }

#pragma unroll
  for (int m = 0; m < 2; m++) {
    float inv[4];
#pragma unroll
    for (int j = 0; j < 4; j++) inv[j] = 1.0f / __shfl(l_r[m], lg * 4 + j);
#pragma unroll
    for (int cb = 0; cb < 8; cb++) {
      int col = h * HD_ + (l16 & 7) * 16 + cb * 2 + (l16 >> 3);
#pragma unroll
      for (int j = 0; j < 4; j++) {
        int row = qb + m * 16 + lg * 4 + j;
        O[(size_t)row * (H_ * HD_) + col] = f2bf(acc[m][cb][j] * inv[j]);
      }
    }
  }
}

// ---------------- combine (img rows only): img_in = bf16(attn[512+r] + ip_out[r]) -------
__global__ void combine_kernel(const unsigned short* __restrict__ attn,
                               const unsigned short* __restrict__ ipo,
                               unsigned short* __restrict__ img_in) {
  size_t i = ((size_t)blockIdx.x * blockDim.x + threadIdx.x) * 8;
  if (i >= (size_t)SIMG_ * D_) return;
  short8 a = *reinterpret_cast<const short8*>(attn + (size_t)LTXT_ * D_ + i);
  short8 b = *reinterpret_cast<const short8*>(ipo + i);
  short8 o;
#pragma unroll
  for (int j = 0; j < 8; j++)
    o[j] = (short)f2bf(bf2f((unsigned short)a[j]) + bf2f((unsigned short)b[j]));
  *reinterpret_cast<short8*>(img_in + i) = o;
}

extern "C" void kernel_launch(void* const* d_in, const int* in_sizes, int n_in,
                              void* d_out, int out_size, void* d_ws, size_t ws_size,
                              hipStream_t stream) {
  const float* hs   = (const float*)d_in[0];
  const float* ehs  = (const float*)d_in[1];
  const float* iphs = (const float*)d_in[2];
  const float* rcos = (const float*)d_in[3];
  const float* rsin = (const float*)d_in[4];
  const float* Wq   = (const float*)d_in[5];  const float* bq   = (const float*)d_in[6];
  const float* Wk   = (const float*)d_in[7];  const float* bk   = (const float*)d_in[8];
  const float* Wv   = (const float*)d_in[9];  const float* bv   = (const float*)d_in[10];
  const float* nqw  = (const float*)d_in[11]; const float* nkw  = (const float*)d_in[12];
  const float* aWq  = (const float*)d_in[13]; const float* abq  = (const float*)d_in[14];
  const float* aWk  = (const float*)d_in[15]; const float* abk  = (const float*)d_in[16];
  const float* aWv  = (const float*)d_in[17]; const float* abv  = (const float*)d_in[18];
  const float* naqw = (const float*)d_in[19]; const float* nakw = (const float*)d_in[20];
  const float* Wkip = (const float*)d_in[21]; const float* bkip = (const float*)d_in[22];
  const float* Wvip = (const float*)d_in[23]; const float* bvip = (const float*)d_in[24];
  const float* nipqw= (const float*)d_in[25]; const float* nipkw= (const float*)d_in[26];
  const float* Wo   = (const float*)d_in[27]; const float* bo   = (const float*)d_in[28];
  const float* Wao  = (const float*)d_in[29]; const float* bao  = (const float*)d_in[30];
  float* out_img = (float*)d_out;
  float* out_enc = out_img + (size_t)SIMG_ * D_;

  // ---- workspace layout (total 141,557,760 B) ----
  char* ws = (char*)d_ws;
  bf16*  Wt      = (bf16*)(ws + 0);                    // 3 slabs x 18,874,368
  unsigned short* attn_bf   = (unsigned short*)(ws + 37748736);   // 15,728,640 (overlay slab2)
  bf16*  qa      = (bf16*)(ws + 56623104);             // 15,728,640
  bf16*  ka      = (bf16*)(ws + 72351744);             // 15,728,640
  bf16*  vaT     = (bf16*)(ws + 88080384);             // 15,728,640  [24][128][2560]
  bf16*  ipq_bf  = (bf16*)(ws + 103809024);            // 12,582,912
  bf16*  ipk_bf  = (bf16*)(ws + 116391936);            //  6,291,456
  bf16*  ipvT   = (bf16*)(ws + 122683392);             //  6,291,456  [24][128][1024]
  bf16*  act_bf  = (bf16*)(ws + 128974848);            // 12,582,912  (hs cast; later enc+ip casts)
  bf16*  enc_bf  = act_bf;                             // first 3,145,728
  bf16*  ip_bf   = act_bf + (size_t)LTXT_ * D_;        // next 4,194,304
  unsigned short* ip_out_bf = (unsigned short*)act_bf; // overlay (dead after ip GEMM)
  bf16*  img_in  = (bf16*)qa;                          // overlay qa (dead after attn)
  if (ws_size < 141557760) return;

  dim3 tb2(16, 32);

  // 1) hs cast + QKV weights transpose + merged QKV GEMM
  cast_kernel<<<SIMG_ * D_ / 4 / 256, 256, 0, stream>>>(hs, (unsigned short*)act_bf, SIMG_ * D_ / 4);
  transpose_cast3_kernel<<<dim3(48, 48, 3), tb2, 0, stream>>>(Wq, Wk, Wv, (unsigned short*)Wt, D_, D_);
  gemm_proj_kernel<<<dim3(16, 72), 256, 0, stream>>>(act_bf, Wt, SIMG_, D_, 0x210,
      bq, bk, bv, rcos, rsin, LTXT_, LTXT_, SALL_,
      (unsigned short*)qa, nqw, (unsigned short*)ipq_bf, nipqw, SIMG_,
      (unsigned short*)ka, nkw, (unsigned short*)vaT);

  // 2) enc + ip casts in one dispatch (act_bf region; hs_bf dead now)
  cast2_kernel<<<(LTXT_ * D_ / 4 + NIP_ * IPD_ / 4 + 255) / 256, 256, 0, stream>>>(
      ehs,  (unsigned short*)enc_bf, LTXT_ * D_ / 4,
      iphs, (unsigned short*)ip_bf,  NIP_ * IPD_ / 4);

  // 3) enc weights + merged enc GEMM
  transpose_cast3_kernel<<<dim3(48, 48, 3), tb2, 0, stream>>>(aWq, aWk, aWv, (unsigned short*)Wt, D_, D_);
  gemm_proj_kernel<<<dim3(4, 72), 256, 0, stream>>>(enc_bf, Wt, LTXT_, D_, 0x210,
      abq, abk, abv, rcos, rsin, 0, 0, SALL_,
      (unsigned short*)qa, naqw, nullptr, nipqw, SIMG_,
      (unsigned short*)ka, nakw, (unsigned short*)vaT);

  // 4) ip weights + merged ip-KV GEMM
  transpose_cast3_kernel<<<dim3(48, 32, 2), tb2, 0, stream>>>(Wkip, Wvip, Wvip, (unsigned short*)Wt, IPD_, D_);
  gemm_proj_kernel<<<dim3(8, 48), 256, 0, stream>>>(ip_bf, Wt, NIP_, IPD_, 0x23,
      bkip, bvip, bvip, nullptr, nullptr, 0, 0, NIP_,
      nullptr, nullptr, nullptr, nullptr, 0,
      (unsigned short*)ipk_bf, nipkw, (unsigned short*)ipvT);

  // 5) Wo + Wao transpose into slabs 0,1 (act_bf now dead -> ip_out_bf overlay OK)
  transpose_cast3_kernel<<<dim3(48, 48, 2), tb2, 0, stream>>>(Wo, Wao, Wao, (unsigned short*)Wt, D_, D_);

  // 6) both attentions in ONE dispatch (864 blocks, LPT: main first)
  attn_kernel<<<dim3(SALL_ / 128 + SIMG_ / 128, H_), 256, 0, stream>>>(
      qa, ka, vaT, attn_bf, SALL_, SALL_, SALL_ / 128,
      ipq_bf, ipk_bf, ipvT, ip_out_bf, SIMG_, NIP_);

  // 7) combine img rows (enc rows feed Wao GEMM directly from attn_bf)
  combine_kernel<<<SIMG_ * D_ / 8 / 256, 256, 0, stream>>>(attn_bf, ip_out_bf, (unsigned short*)img_in);

  // 8) merged output projections (img + enc in one dispatch)
  gemm_out2_kernel<<<dim3(20, 24), 256, 0, stream>>>(img_in, (const bf16*)attn_bf, Wt,
                                                     bo, bao, out_img, out_enc);
}